// Round 13
// baseline (221.360 us; speedup 1.0000x reference)
//
#include <hip/hip_runtime.h>
#include <hip/hip_bf16.h>

// Conv2dKan, fused barrier-free MFMA kernel. b=16, cin=cout=64, H=W=32, K=3, PAD=1, BASIS=8.
// out[b,o,pix] = bias[o] + sum_{i,k,s8} Wt[i,k,o,s]*act(x[b,i,pix+off(k)])[s]
//   Wt[...,0]=w, Wt[...,s]=w*c[s] (s=1..7) bf16, layout [i][kpos][o][s]
//   act(x) = [silu(x), T1..T7(tanh x)] bf16; act(pad) = act(0) = [0,0,-1,0,1,0,-1,0]
//   bias[o] = sum_{i,k} w*c[...,0]  (T0==1)
// MFMA 16x16x32 bf16 (layouts HW-verified R3/R5): A/B: lane=(quad,l16), k=quad*8+s;
//   C/D: col=l16, row=quad*4+r.
// R13: MEASUREMENT ROUND #2. R12 kernel byte-identical except the whole body
//   repeats 8x (idempotent; trailing barrier isolates reps). Purpose: split
//   cold-L2 (rep 1; harness's 268MB ws-poison fill evicts L2 every iteration)
//   from warm steady-state (reps 2-8), and surface this kernel's counters in
//   top-5. Verdict: total ~145-180us => cold-miss-dominated (R14: prefetch
//   storm / accept floor); total ~250+us => genuinely warm-bound (R14: wf L1
//   grouping via same-kq wave blocks, 2-row waves, act cost halving).

#define CIN   64
#define COUT  64
#define HW    32
#define LL    1024
#define NS    8
#define REPEAT 8

typedef __attribute__((ext_vector_type(8))) short short8;
typedef __attribute__((ext_vector_type(4))) float f32x4;

// ws layout (bytes):
//   [0)       Wt   : 64*9*64*8 bf16 = 589824 B   ([i][kpos][o][s])
//   [589824)  bias : 64 f32         = 256 B

__global__ void prep_kernel(const float* __restrict__ w,
                            const float* __restrict__ c,
                            __hip_bfloat16* __restrict__ Wt,
                            float* __restrict__ bias) {
    int bx = blockIdx.x;
    if (bx >= 144) {
        // bias part: 64 parallel blocks, one o each; 64-lane wave reduce over i.
        const int o = bx - 144;
        const int i = threadIdx.x;
        if (i >= 64) return;
        float v = 0.f;
#pragma unroll
        for (int k = 0; k < 9; ++k) {
            const int idx = (i * COUT + o) * 9 + k;
            v += w[idx] * c[idx * 8];
        }
#pragma unroll
        for (int off = 32; off > 0; off >>= 1) v += __shfl_down(v, off);
        if (i == 0) bias[o] = v;
        return;
    }
    // Wt part: 144 blocks
    const int tid = bx * 256 + threadIdx.x;   // < 36864 = 64i*9k*64o
    const int i = tid / (9 * COUT);
    const int r = tid - i * 9 * COUT;
    const int k = r / COUT;
    const int o = r - k * COUT;
    const int widx = (i * COUT + o) * 9 + k;
    const float wv = w[widx];
    __hip_bfloat16* dst = Wt + (size_t)tid * NS;   // tid == (i*9+k)*64+o
    dst[0] = __float2bfloat16(wv);
#pragma unroll
    for (int s = 1; s < 8; ++s) dst[s] = __float2bfloat16(wv * c[widx * 8 + s]);
}

// grid (16 b, 32 rows, 2 o-halves) -- x=b so lin%8=b%8 (XCD L2 locality).
// block 256 = 4 INDEPENDENT waves = 4 K-quarters. Wave: 32pix(row) x 32o x 16ch.
__global__ __launch_bounds__(256, 4) void kan_fused_kernel(
        const float* __restrict__ x,
        const __hip_bfloat16* __restrict__ Wt,
        const float* __restrict__ bias,
        float* __restrict__ out) {
    // 4 x 3264 ushorts per-wave act scratch [ch4][row3][col34] x 16B = 26112 B
    // epilogue overlay: float red[kq4][pix32][o 33pad] = 16896 B
    __shared__ __align__(16) unsigned short Wlds[13056];

    const int tid   = threadIdx.x;
    const int wv    = tid >> 6;       // = kq (K-quarter)
    const int lane  = tid & 63;
    const int quad  = lane >> 4;      // channel within 4-ch chunk
    const int l16   = lane & 15;

    const int b   = blockIdx.x;
    const int row = blockIdx.y;
    const int oh  = blockIdx.z;       // o-half: [oh*32, oh*32+32)

    const unsigned short* WtU = (const unsigned short*)Wt;
    unsigned short* scratch = Wlds + wv * 3264;   // 408 cells x 8 ushorts

    for (int rep = 0; rep < REPEAT; ++rep) {   // R13: repeat for rocprof visibility

    f32x4 acc[2][2];                  // [h pixel-group][nt]
#pragma unroll
    for (int h = 0; h < 2; ++h)
#pragma unroll
        for (int nt = 0; nt < 2; ++nt) acc[h][nt] = (f32x4){0.f, 0.f, 0.f, 0.f};

    for (int chunk = 0; chunk < 4; ++chunk) {
        const int chbase = wv * 16 + chunk * 4;
        // ---- recompute this chunk's activations into private scratch (408 cells).
        //      No barrier: scratch is per-wave; lgkmcnt waits are automatic. ----
#pragma unroll
        for (int p = 0; p < 7; ++p) {
            const int cell = p * 64 + lane;
            if (cell < 408) {
                const int ch  = cell / 102;
                const int rem = cell - ch * 102;
                const int r3  = rem / 34;
                const int col = rem - r3 * 34;
                const int gy  = row - 1 + r3;
                const int gx  = col - 1;
                __align__(16) unsigned int u[4];
                if ((unsigned)gy < 32u && (unsigned)gx < 32u) {
                    const float xv = x[((size_t)(b * CIN + chbase + ch) * HW + gy) * HW + gx];
                    const float e   = __expf(-xv);
                    const float res = xv / (1.f + e);          // silu
                    const float e2  = __expf(2.f * xv);
                    const float t   = 1.f - 2.f / (e2 + 1.f);  // tanh
                    const float T2 = 2.f * t * t  - 1.f;
                    const float T3 = 2.f * t * T2 - t;
                    const float T4 = 2.f * t * T3 - T2;
                    const float T5 = 2.f * t * T4 - T3;
                    const float T6 = 2.f * t * T5 - T4;
                    const float T7 = 2.f * t * T6 - T5;
                    __hip_bfloat16* hv = (__hip_bfloat16*)u;
                    hv[0] = __float2bfloat16(res); hv[1] = __float2bfloat16(t);
                    hv[2] = __float2bfloat16(T2);  hv[3] = __float2bfloat16(T3);
                    hv[4] = __float2bfloat16(T4);  hv[5] = __float2bfloat16(T5);
                    hv[6] = __float2bfloat16(T6);  hv[7] = __float2bfloat16(T7);
                } else {
                    // act(0): [0, 0, -1, 0, 1, 0, -1, 0]
                    u[0] = 0x00000000u; u[1] = 0x0000BF80u;
                    u[2] = 0x00003F80u; u[3] = 0x0000BF80u;
                }
                *(float4*)(scratch + cell * 8) = *(const float4*)u;
            }
        }

        // ---- MFMA: af from private scratch, wf straight from global (L2) ----
        const unsigned short* wchunk = WtU +
            ((size_t)(chbase + quad) * 9 * COUT + (oh << 5) + l16) * NS;
#pragma unroll
        for (int kpos = 0; kpos < 9; ++kpos) {
            const int dy = kpos / 3 - 1, dx = kpos % 3 - 1;
            const int cb = quad * 102 + (dy + 1) * 34 + (dx + 1);
            short8 af0 = *(const short8*)(scratch + (cb + l16) * 8);
            short8 af1 = *(const short8*)(scratch + (cb + 16 + l16) * 8);
#pragma unroll
            for (int nt = 0; nt < 2; ++nt) {
                short8 wf = *(const short8*)(wchunk + (kpos * COUT + nt * 16) * NS);
                acc[0][nt] = __builtin_amdgcn_mfma_f32_16x16x32_bf16(wf, af0, acc[0][nt], 0, 0, 0);
                acc[1][nt] = __builtin_amdgcn_mfma_f32_16x16x32_bf16(wf, af1, acc[1][nt], 0, 0, 0);
            }
        }
    }

    // ---- epilogue: reduce 4 K-quarters via padded LDS, single barrier pair ----
    __syncthreads();   // all waves done with private scratch before overlay
    float* red = (float*)Wlds;       // red[kq][pix32][33]
#pragma unroll
    for (int h = 0; h < 2; ++h)
#pragma unroll
        for (int nt = 0; nt < 2; ++nt)
#pragma unroll
            for (int r = 0; r < 4; ++r) {
                const int p  = h * 16 + l16;
                const int ol = nt * 16 + quad * 4 + r;
                red[(wv * 32 + p) * 33 + ol] = acc[h][nt][r];
            }
    __syncthreads();

#pragma unroll
    for (int rep2 = 0; rep2 < 4; ++rep2) {
        const int v  = rep2 * 256 + tid;   // 1024 = 32 pix x 32 o
        const int p  = v & 31;
        const int ol = v >> 5;
        const int o  = (oh << 5) + ol;
        const float s = red[p * 33 + ol] + red[(32 + p) * 33 + ol]
                      + red[(64 + p) * 33 + ol] + red[(96 + p) * 33 + ol] + bias[o];
        out[(size_t)(b * COUT + o) * LL + row * HW + p] = s;
    }

    __syncthreads();   // isolate reps: red reads done before next rep's scratch writes
    }  // rep
}

extern "C" void kernel_launch(void* const* d_in, const int* in_sizes, int n_in,
                              void* d_out, int out_size, void* d_ws, size_t ws_size,
                              hipStream_t stream) {
    const float* x = (const float*)d_in[0];
    const float* w = (const float*)d_in[1];
    const float* c = (const float*)d_in[2];
    float* out = (float*)d_out;

    char* ws = (char*)d_ws;
    __hip_bfloat16* Wt   = (__hip_bfloat16*)(ws);
    float*          bias = (float*)(ws + 589824);

    prep_kernel<<<208, 256, 0, stream>>>(w, c, Wt, bias);
    kan_fused_kernel<<<dim3(16, 32, 2), 256, 0, stream>>>(x, Wt, bias, out);
}

// Round 14
// 79.564 us; speedup vs baseline: 2.7822x; 2.7822x over previous
//
#include <hip/hip_runtime.h>
#include <hip/hip_bf16.h>

// Conv2dKan, fused MFMA kernel. b=16, cin=cout=64, H=W=32, K=3, PAD=1, BASIS=8.
// out[b,o,pix] = bias[o] + sum_{i,k,s8} Wt[i,k,o,s]*act(x[b,i,pix+off(k)])[s]
//   Wt[...,0]=w, Wt[...,s]=w*c[s] (s=1..7) bf16, layout [i][kpos][o][s]
//   act(x) = [silu(x), T1..T7(tanh x)] bf16; act(pad) = act(0) = [0,0,-1,0,1,0,-1,0]
//   bias[o] = sum_{i,k} w*c[...,0]  (T0==1)
// MFMA 16x16x32 bf16 (layouts HW-verified R3/R5): A/B: lane=(quad,l16), k=quad*8+s;
//   C/D: col=l16, row=quad*4+r.
// R14 (from R13 measurement: warm rep 19.4us with VALUBusy 62% (act recompute:
//   full-div sequences, scalar cvt, 6x redundancy), 4.4 extra cyc/af-read bank
//   conflicts, cold rep 42us from post-fill L3 eviction):
//   1) block = 512thr = 8 waves (kq4 x oh2); oh-pair SHARES double-buffered act
//      scratch (each computes half) -> act work halved; 1 barrier/chunk;
//      512 blocks x 8 waves = 4096 waves = 4/SIMD, 2 blocks/CU (LDS 52224B).
//   2) act math: v_rcp instead of fp32 div, packed bf16 converts, branchless
//      r3 decode -> per-cell VALU ~x0.6.
//   3) scratch layout [pos][ch] interleaved -> af ds_read_b128 covers contiguous
//      1024B across the wave (conflict-free); x prefetch blocks in prep re-warm
//      x into L3 after the harness's 268MB ws-poison fill (Wt is L3-warm from
//      prep's own writeback).

#define CIN   64
#define COUT  64
#define HW    32
#define LL    1024
#define NS    8

typedef __attribute__((ext_vector_type(8))) short short8;
typedef __attribute__((ext_vector_type(4))) float f32x4;

// ws layout (bytes):
//   [0)       Wt    : 64*9*64*8 bf16 = 589824 B   ([i][kpos][o][s])
//   [589824)  bias  : 64 f32         = 256 B
//   [590080)  dummy : keep-alive sink for prefetch

__global__ void prep_kernel(const float* __restrict__ w,
                            const float* __restrict__ c,
                            __hip_bfloat16* __restrict__ Wt,
                            float* __restrict__ bias,
                            const float* __restrict__ x,
                            float* __restrict__ dummy) {
    const int bx = blockIdx.x;
    if (bx < 144) {
        // Wt part
        const int tid = bx * 256 + threadIdx.x;   // < 36864 = 64i*9k*64o
        const int i = tid / (9 * COUT);
        const int r = tid - i * 9 * COUT;
        const int k = r / COUT;
        const int o = r - k * COUT;
        const int widx = (i * COUT + o) * 9 + k;
        const float wv = w[widx];
        __hip_bfloat16* dst = Wt + (size_t)tid * NS;   // tid == (i*9+k)*64+o
        dst[0] = __float2bfloat16(wv);
#pragma unroll
        for (int s = 1; s < 8; ++s) dst[s] = __float2bfloat16(wv * c[widx * 8 + s]);
        return;
    }
    if (bx < 208) {
        // bias part: 64 blocks, one o each; 64-lane wave reduce over i.
        const int o = bx - 144;
        const int i = threadIdx.x;
        if (i >= 64) return;
        float v = 0.f;
#pragma unroll
        for (int k = 0; k < 9; ++k) {
            const int idx = (i * COUT + o) * 9 + k;
            v += w[idx] * c[idx * 8];
        }
#pragma unroll
        for (int off = 32; off > 0; off >>= 1) v += __shfl_down(v, off);
        if (i == 0) bias[o] = v;
        return;
    }
    // x-prefetch part: 1024 blocks, each touches one (b,ch) 4KB image -> L3 warm.
    const int idx = bx - 208;          // [0,1024)
    const int r  = idx & 7;
    const int m  = idx >> 3;
    const int b  = r + 8 * (m & 1);
    const int ch = m >> 1;
    const float4 v = ((const float4*)(x + (size_t)(b * CIN + ch) * LL))[threadIdx.x];
    const float acc = v.x + v.y + v.z + v.w;
    if (acc == 1.0e-37f) dummy[threadIdx.x] = acc;   // keep-alive; never taken in practice
}

// grid (16 b, 32 rows), block 512 = 8 waves = (kq4 x oh2). Wave: 32pix x 32o x 16ch.
__global__ __launch_bounds__(512, 4) void kan_fused_kernel(
        const float* __restrict__ x,
        const __hip_bfloat16* __restrict__ Wt,
        const float* __restrict__ bias,
        float* __restrict__ out) {
    // double-buffered act scratch: 2 x [kq4][pos102][ch4] x 16B = 2 x 26112 B
    //   (interleaved [pos][ch] -> af reads are contiguous 1024B per wave)
    // epilogue overlay: float red[kq4][pix32][o 65pad] = 33280 B
    __shared__ __align__(16) unsigned short Wlds[26112];   // 52224 B

    const int tid   = threadIdx.x;
    const int wv    = tid >> 6;
    const int lane  = tid & 63;
    const int quad  = lane >> 4;      // channel within 4-ch chunk
    const int l16   = lane & 15;
    const int kq    = wv >> 1;        // K-quarter: channels [kq*16, kq*16+16)
    const int oh    = wv & 1;         // o-half: [oh*32, oh*32+32)

    const int b   = blockIdx.x;
    const int row = blockIdx.y;

    const unsigned short* WtU = (const unsigned short*)Wt;

    f32x4 acc[2][2];                  // [h pixel-group][nt]
#pragma unroll
    for (int h = 0; h < 2; ++h)
#pragma unroll
        for (int nt = 0; nt < 2; ++nt) acc[h][nt] = (f32x4){0.f, 0.f, 0.f, 0.f};

    for (int chunk = 0; chunk < 4; ++chunk) {
        const int chbase = kq * 16 + chunk * 4;
        unsigned short* usd = Wlds + (chunk & 1) * 13056 + kq * 3264;

        // ---- act: oh-pair splits the 408 cells by slot parity (4 slots each) ----
#pragma unroll
        for (int p = 0; p < 4; ++p) {
            const int cell = (p * 2 + oh) * 64 + lane;
            if (cell < 408) {
                const int ch  = cell & 3;          // interleaved layout [pos][ch]
                const int pos = cell >> 2;         // 0..101
                const int r3  = (pos >= 68) ? 2 : ((pos >= 34) ? 1 : 0);
                const int col = pos - r3 * 34;
                const int gy  = row - 1 + r3;
                const int gx  = col - 1;
                union { __hip_bfloat162 h2[4]; float4 f4; unsigned int u[4]; } U;
                if ((unsigned)gy < 32u && (unsigned)gx < 32u) {
                    const float xv = x[((size_t)(b * CIN + chbase + ch) * HW + gy) * HW + gx];
                    const float em  = __expf(-xv);
                    const float res = xv * __builtin_amdgcn_rcpf(1.f + em);     // silu
                    const float e2  = __expf(2.f * xv);
                    const float t   = 1.f - 2.f * __builtin_amdgcn_rcpf(e2 + 1.f); // tanh
                    const float t2  = t + t;
                    const float T2 = __builtin_fmaf(t2, t,  -1.f);
                    const float T3 = __builtin_fmaf(t2, T2, -t);
                    const float T4 = __builtin_fmaf(t2, T3, -T2);
                    const float T5 = __builtin_fmaf(t2, T4, -T3);
                    const float T6 = __builtin_fmaf(t2, T5, -T4);
                    const float T7 = __builtin_fmaf(t2, T6, -T5);
                    U.h2[0] = __float22bfloat162_rn(make_float2(res, t));
                    U.h2[1] = __float22bfloat162_rn(make_float2(T2, T3));
                    U.h2[2] = __float22bfloat162_rn(make_float2(T4, T5));
                    U.h2[3] = __float22bfloat162_rn(make_float2(T6, T7));
                } else {
                    // act(0): pairs (0,0), (-1,0), (1,0), (-1,0)
                    U.u[0] = 0x00000000u; U.u[1] = 0x0000BF80u;
                    U.u[2] = 0x00003F80u; U.u[3] = 0x0000BF80u;
                }
                *(float4*)(usd + cell * 8) = U.f4;
            }
        }
        __syncthreads();   // oh-pair's scratch halves complete (dbuf: no 2nd barrier)

        // ---- MFMA: af from shared scratch (contiguous lanes), wf from global L2 ----
        const unsigned short* wchunk = WtU +
            ((size_t)(chbase + quad) * 9 * COUT + (oh << 5) + l16) * NS;
#pragma unroll
        for (int kpos = 0; kpos < 9; ++kpos) {
            const int dy = kpos / 3 - 1, dx = kpos % 3 - 1;
            const int posb = (dy + 1) * 34 + (dx + 1);
            short8 af0 = *(const short8*)(usd + ((posb + l16) * 4 + quad) * 8);
            short8 af1 = *(const short8*)(usd + ((posb + 16 + l16) * 4 + quad) * 8);
#pragma unroll
            for (int nt = 0; nt < 2; ++nt) {
                short8 wf = *(const short8*)(wchunk + (kpos * COUT + nt * 16) * NS);
                acc[0][nt] = __builtin_amdgcn_mfma_f32_16x16x32_bf16(wf, af0, acc[0][nt], 0, 0, 0);
                acc[1][nt] = __builtin_amdgcn_mfma_f32_16x16x32_bf16(wf, af1, acc[1][nt], 0, 0, 0);
            }
        }
    }

    // ---- epilogue: reduce 4 K-quarters via padded LDS ----
    __syncthreads();   // all waves' last-chunk reads consumed before overlay
    float* red = (float*)Wlds;       // red[kq][pix32][65]
#pragma unroll
    for (int h = 0; h < 2; ++h)
#pragma unroll
        for (int nt = 0; nt < 2; ++nt)
#pragma unroll
            for (int r = 0; r < 4; ++r) {
                const int p = h * 16 + l16;
                const int o = (oh << 5) + nt * 16 + quad * 4 + r;
                red[(kq * 32 + p) * 65 + o] = acc[h][nt][r];
            }
    __syncthreads();

#pragma unroll
    for (int rep = 0; rep < 4; ++rep) {
        const int v = rep * 512 + tid;    // 2048 = 32 pix x 64 o
        const int p = v & 31;
        const int o = v >> 5;
        const float s = red[p * 65 + o] + red[(32 + p) * 65 + o]
                      + red[(64 + p) * 65 + o] + red[(96 + p) * 65 + o] + bias[o];
        out[(size_t)(b * COUT + o) * LL + row * HW + p] = s;
    }
}

extern "C" void kernel_launch(void* const* d_in, const int* in_sizes, int n_in,
                              void* d_out, int out_size, void* d_ws, size_t ws_size,
                              hipStream_t stream) {
    const float* x = (const float*)d_in[0];
    const float* w = (const float*)d_in[1];
    const float* c = (const float*)d_in[2];
    float* out = (float*)d_out;

    char* ws = (char*)d_ws;
    __hip_bfloat16* Wt   = (__hip_bfloat16*)(ws);
    float*          bias = (float*)(ws + 589824);
    float*          dummy = (float*)(ws + 590080);

    // 144 Wt + 64 bias + 1024 x-prefetch = 1232 blocks, all parallel
    prep_kernel<<<1232, 256, 0, stream>>>(w, c, Wt, bias, x, dummy);
    kan_fused_kernel<<<dim3(16, 32), 512, 0, stream>>>(x, Wt, bias, out);
}